// Round 1
// baseline (189.415 us; speedup 1.0000x reference)
//
#include <hip/hip_runtime.h>

// ---------------------------------------------------------------------------
// T5Attention forward: out = (softmax(Q K^T + bias) V) Wo
// B=2, S=2048, D=1024, H=16, DK=64, buckets=32, max_dist=128
// Strategy: bf16 MFMA (16x16x32) everywhere, fp32 accumulate.
// ---------------------------------------------------------------------------

typedef __attribute__((ext_vector_type(8)))  unsigned short u16x8;
typedef __attribute__((ext_vector_type(4)))  unsigned short u16x4;
typedef __attribute__((ext_vector_type(8)))  __bf16         bf16x8;
typedef __attribute__((ext_vector_type(4)))  float          f32x4;

#define GLOBAL_AS __attribute__((address_space(1)))
#define LDS_AS    __attribute__((address_space(3)))

static __device__ inline f32x4 MFMA(u16x8 a, u16x8 b, f32x4 c) {
  return __builtin_amdgcn_mfma_f32_16x16x32_bf16(
      __builtin_bit_cast(bf16x8, a), __builtin_bit_cast(bf16x8, b), c, 0, 0, 0);
}

static __device__ inline void gload16(const void* g, void* l) {
  __builtin_amdgcn_global_load_lds((const GLOBAL_AS unsigned int*)g,
                                   (LDS_AS unsigned int*)l, 16, 0, 0);
}

// float -> bf16 bits, round-to-nearest-even
static __device__ inline unsigned short f2bf(float x) {
  unsigned int u = __builtin_bit_cast(unsigned int, x);
  u = (u + 0x7FFFu + ((u >> 16) & 1u)) >> 16;
  return (unsigned short)u;
}

// ---------------------------------------------------------------------------
// prep: fp32 -> bf16 convert (vectorized)
__global__ void k_cvt(const float* __restrict__ src, unsigned short* __restrict__ dst, int n4) {
  int i = blockIdx.x * blockDim.x + threadIdx.x;
  if (i >= n4) return;
  float4 v = *(const float4*)(src + (size_t)i * 4);
  u16x4 o;
  o[0] = f2bf(v.x); o[1] = f2bf(v.y); o[2] = f2bf(v.z); o[3] = f2bf(v.w);
  *(u16x4*)(dst + (size_t)i * 4) = o;
}

// prep: transpose+convert  src fp32 [K][N] row-major -> dst bf16 [N][K] row-major
__global__ __launch_bounds__(256) void k_tc(const float* __restrict__ src,
                                            unsigned short* __restrict__ dst,
                                            int K, int N) {
  __shared__ float tile[64][65];
  int k0 = blockIdx.y << 6, n0 = blockIdx.x << 6;
  int t = threadIdx.x;
  int rr = t >> 4, cc = (t & 15) << 2;
#pragma unroll
  for (int j = 0; j < 4; j++) {
    float4 v = *(const float4*)(src + (size_t)(k0 + rr + j * 16) * N + n0 + cc);
    tile[rr + j * 16][cc + 0] = v.x;
    tile[rr + j * 16][cc + 1] = v.y;
    tile[rr + j * 16][cc + 2] = v.z;
    tile[rr + j * 16][cc + 3] = v.w;
  }
  __syncthreads();
#pragma unroll
  for (int j = 0; j < 4; j++) {
    int n = rr + j * 16;
    u16x4 o;
    o[0] = f2bf(tile[cc + 0][n]);
    o[1] = f2bf(tile[cc + 1][n]);
    o[2] = f2bf(tile[cc + 2][n]);
    o[3] = f2bf(tile[cc + 3][n]);
    *(u16x4*)(dst + (size_t)(n0 + n) * K + k0 + cc) = o;
  }
}

// prep: bias table  btab[h*4095 + (rel_pos+2047)] = rel_emb[bucket(rel_pos)][h]
__global__ void k_bias(const float* __restrict__ rel_emb, float* __restrict__ btab) {
  int i = blockIdx.x * blockDim.x + threadIdx.x;
  if (i >= 16 * 4095) return;
  int h = i / 4095;
  int rp = i % 4095 - 2047;          // rel_pos = key - query
  int rb = rp > 0 ? 16 : 0;
  int arp = rp < 0 ? -rp : rp;
  int v;
  if (arp < 8) {
    v = arp;
  } else {
    float t = logf((float)arp * 0.125f);
    t = t / 2.772588722239781f;      // log(128/8) in f32
    t = t * 8.0f;
    v = 8 + (int)t;
    if (v > 15) v = 15;
  }
  btab[i] = rel_emb[(rb + v) * 16 + h];
}

// ---------------------------------------------------------------------------
// GEMM: C[M,N] = A[M,K](bf16) * Bt[N,K](bf16, pre-transposed)
// 128x128 tile, BK=64, 4 waves (2x2 of 64x64), 16x16x32 MFMA.
// EPI=0: scatter bf16 into qkv planes [which][b,h,s,d]; EPI=1: fp32 row-major out.
template <int EPI>
__global__ __launch_bounds__(256) void k_gemm(const unsigned short* __restrict__ A,
                                              const unsigned short* __restrict__ Bt,
                                              void* __restrict__ outp,
                                              int M, int N, int K) {
  __shared__ __attribute__((aligned(16))) char smem[32768];
  const int tid = threadIdx.x;
  const int lane = tid & 63, w = tid >> 6;
  const int l15 = lane & 15, g = lane >> 4;
  const int wr = w >> 1, wc = w & 1;
  const int bm0 = blockIdx.y << 7, bn0 = blockIdx.x << 7;

  const char* Ag = (const char*)A + (size_t)bm0 * K * 2;
  const char* Bg = (const char*)Bt + (size_t)bn0 * K * 2;

  f32x4 acc[4][4];
#pragma unroll
  for (int i = 0; i < 4; i++)
#pragma unroll
    for (int j = 0; j < 4; j++) acc[i][j] = (f32x4)0.0f;

  const int rowA = wr * 64 + l15;
  const int rowB = wc * 64 + l15;
  const int swz = (l15 & 7) << 4;

  for (int kt = 0; kt < K; kt += 64) {
#pragma unroll
    for (int j = 0; j < 4; j++) {
      int idx = ((j * 4 + w) << 10) + (lane << 4);
      int row = idx >> 7;
      int gs = (idx >> 4) & 7;
      size_t co = (size_t)row * (K * 2) + kt * 2 + ((gs ^ (row & 7)) << 4);
      gload16(Ag + co, smem + ((j * 4 + w) << 10));
      gload16(Bg + co, smem + 16384 + ((j * 4 + w) << 10));
    }
    __syncthreads();
#pragma unroll
    for (int kk = 0; kk < 2; kk++) {
      const int cp = ((kk << 6) + (g << 4)) ^ swz;
      u16x8 af[4], bfv[4];
#pragma unroll
      for (int mt = 0; mt < 4; mt++)
        af[mt] = *(const u16x8*)(smem + ((rowA + mt * 16) << 7) + cp);
#pragma unroll
      for (int nt = 0; nt < 4; nt++)
        bfv[nt] = *(const u16x8*)(smem + 16384 + ((rowB + nt * 16) << 7) + cp);
#pragma unroll
      for (int mt = 0; mt < 4; mt++)
#pragma unroll
        for (int nt = 0; nt < 4; nt++)
          acc[mt][nt] = MFMA(af[mt], bfv[nt], acc[mt][nt]);
    }
    __syncthreads();
  }

#pragma unroll
  for (int mt = 0; mt < 4; mt++) {
#pragma unroll
    for (int nt = 0; nt < 4; nt++) {
#pragma unroll
      for (int r = 0; r < 4; r++) {
        int m = bm0 + wr * 64 + mt * 16 + g * 4 + r;
        int n = bn0 + wc * 64 + nt * 16 + l15;
        float val = acc[mt][nt][r];
        if (EPI == 0) {
          int which = n >> 10;
          int h = (n >> 6) & 15;
          int d = n & 63;
          int b = m >> 11, s = m & 2047;
          unsigned short* o = (unsigned short*)outp;
          o[(size_t)which * 4194304 + ((size_t)((b * 16 + h) * 2048 + s)) * 64 + d] = f2bf(val);
        } else {
          ((float*)outp)[(size_t)m * N + n] = val;
        }
      }
    }
  }
}

// ---------------------------------------------------------------------------
// Flash attention. Grid: (S/128, B*H). Block: 512 thr = 8 waves; wave = 16 q rows.
// qkv: 3 planes of [B*H][2048][64] bf16 (q, k, v). ctx out: [B*S][1024] bf16.
__global__ __launch_bounds__(512) void k_attn(const unsigned short* __restrict__ qkv,
                                              const float* __restrict__ btab,
                                              unsigned short* __restrict__ ctx) {
  __shared__ __attribute__((aligned(16))) char smem[32768]; // K:0..8K, Vt:8K..16K, P: 16K..32K
  const int tid = threadIdx.x;
  const int lane = tid & 63, w = tid >> 6;
  const int l15 = lane & 15, g = lane >> 4;
  const int plane = blockIdx.y;
  const int h = plane & 15, b = plane >> 4;
  const int q0 = (blockIdx.x << 7) + (w << 4);

  const unsigned short* Qp = qkv + (size_t)plane * 131072;
  const unsigned short* Kp = Qp + 4194304;
  const unsigned short* Vp = Qp + 8388608;

  u16x8 qa[2];
#pragma unroll
  for (int kk = 0; kk < 2; kk++)
    qa[kk] = *(const u16x8*)(Qp + (size_t)(q0 + l15) * 64 + kk * 32 + g * 8);

  float m_r[4], l_r[4];
  f32x4 oacc[4];
#pragma unroll
  for (int r = 0; r < 4; r++) { m_r[r] = -1e30f; l_r[r] = 0.0f; }
#pragma unroll
  for (int t = 0; t < 4; t++) oacc[t] = (f32x4)0.0f;

  const float* brow = btab + h * 4095 + 2047 - q0;
  const float LOG2E = 1.4426950408889634f;

  for (int kv = 0; kv < 2048; kv += 64) {
    { // stage K tile [64][64] via global_load_lds, source pre-swizzled
      int row = tid >> 3, gs = tid & 7;
      gload16((const char*)Kp + (size_t)(kv + row) * 128 + ((gs ^ (row & 7)) << 4),
              smem + (w << 10));
    }
    { // stage V transposed: Vt[d][key], swizzled
      int key = tid & 63, dblk = tid >> 6;
      u16x8 vv = *(const u16x8*)(Vp + (size_t)(kv + key) * 64 + dblk * 8);
#pragma unroll
      for (int j = 0; j < 8; j++) {
        int d = dblk * 8 + j;
        *(unsigned short*)(smem + 8192 + (d << 7) + ((key * 2) ^ ((d & 7) << 4))) =
            (unsigned short)vv[j];
      }
    }
    __syncthreads();

    // S = Q K^T  (16 q-rows x 64 keys)
    f32x4 s[4];
#pragma unroll
    for (int nt = 0; nt < 4; nt++) {
      int keyr = nt * 16 + l15;
      int sw = (keyr & 7) << 4;
      u16x8 kb0 = *(const u16x8*)(smem + (keyr << 7) + ((g << 4) ^ sw));
      u16x8 kb1 = *(const u16x8*)(smem + (keyr << 7) + ((64 + (g << 4)) ^ sw));
      f32x4 z = (f32x4)0.0f;
      z = MFMA(qa[0], kb0, z);
      z = MFMA(qa[1], kb1, z);
      s[nt] = z;
    }
    // + position bias
#pragma unroll
    for (int nt = 0; nt < 4; nt++)
#pragma unroll
      for (int r = 0; r < 4; r++)
        s[nt][r] += brow[(kv + nt * 16 + l15) - (g * 4 + r)];

    // online softmax (rows live on lanes sharing g; reduce across l15)
    float alpha[4];
#pragma unroll
    for (int r = 0; r < 4; r++) {
      float mx = fmaxf(fmaxf(s[0][r], s[1][r]), fmaxf(s[2][r], s[3][r]));
      mx = fmaxf(mx, __shfl_xor(mx, 1));
      mx = fmaxf(mx, __shfl_xor(mx, 2));
      mx = fmaxf(mx, __shfl_xor(mx, 4));
      mx = fmaxf(mx, __shfl_xor(mx, 8));
      float mn = fmaxf(m_r[r], mx);
      alpha[r] = exp2f((m_r[r] - mn) * LOG2E);
      m_r[r] = mn;
    }
#pragma unroll
    for (int nt = 0; nt < 4; nt++)
#pragma unroll
      for (int r = 0; r < 4; r++)
        s[nt][r] = exp2f((s[nt][r] - m_r[r]) * LOG2E);
#pragma unroll
    for (int r = 0; r < 4; r++) {
      float su = s[0][r] + s[1][r] + s[2][r] + s[3][r];
      su += __shfl_xor(su, 1);
      su += __shfl_xor(su, 2);
      su += __shfl_xor(su, 4);
      su += __shfl_xor(su, 8);
      l_r[r] = l_r[r] * alpha[r] + su;
    }
#pragma unroll
    for (int t = 0; t < 4; t++) {
      f32x4 o = oacc[t];
      o[0] *= alpha[0]; o[1] *= alpha[1]; o[2] *= alpha[2]; o[3] *= alpha[3];
      oacc[t] = o;
    }

    // P -> per-wave LDS buffer (transpose to MFMA A layout), swizzled rows
    char* Pb = smem + 16384 + (w << 11);
#pragma unroll
    for (int nt = 0; nt < 4; nt++)
#pragma unroll
      for (int r = 0; r < 4; r++) {
        int qq = g * 4 + r;
        *(unsigned short*)(Pb + (qq << 7) + (((nt * 16 + l15) * 2) ^ ((qq & 7) << 4))) =
            f2bf(s[nt][r]);
      }
    asm volatile("s_waitcnt lgkmcnt(0)" ::: "memory");
    __builtin_amdgcn_sched_barrier(0);

    u16x8 pa[2];
#pragma unroll
    for (int kk = 0; kk < 2; kk++)
      pa[kk] = *(const u16x8*)(Pb + (l15 << 7) + (((kk << 6) + (g << 4)) ^ ((l15 & 7) << 4)));

    // O += P V
#pragma unroll
    for (int t = 0; t < 4; t++) {
      int d = t * 16 + l15;
      int sw = (d & 7) << 4;
      u16x8 vb0 = *(const u16x8*)(smem + 8192 + (d << 7) + ((g << 4) ^ sw));
      u16x8 vb1 = *(const u16x8*)(smem + 8192 + (d << 7) + ((64 + (g << 4)) ^ sw));
      oacc[t] = MFMA(pa[0], vb0, oacc[t]);
      oacc[t] = MFMA(pa[1], vb1, oacc[t]);
    }
    __syncthreads();
  }

#pragma unroll
  for (int r = 0; r < 4; r++) {
    float inv = 1.0f / l_r[r];
    size_t rowoff = ((size_t)(b * 2048 + q0 + g * 4 + r) << 10) + h * 64;
#pragma unroll
    for (int t = 0; t < 4; t++)
      ctx[rowoff + t * 16 + l15] = f2bf(oacc[t][r] * inv);
  }
}

// ---------------------------------------------------------------------------
extern "C" void kernel_launch(void* const* d_in, const int* in_sizes, int n_in,
                              void* d_out, int out_size, void* d_ws, size_t ws_size,
                              hipStream_t stream) {
  const float* hs = (const float*)d_in[0];
  const float* wq = (const float*)d_in[1];
  const float* wk = (const float*)d_in[2];
  const float* wv = (const float*)d_in[3];
  const float* wo = (const float*)d_in[4];
  const float* re = (const float*)d_in[5];

  if (ws_size < 50593728u) return;

  char* ws = (char*)d_ws;
  unsigned short* hsb = (unsigned short*)(ws);              // [4096][1024] bf16
  unsigned short* wt  = (unsigned short*)(ws + 8388608);    // [3072][1024] bf16 (wq,wk,wv ^T)
  unsigned short* wot = (unsigned short*)(ws + 14680064);   // [1024][1024] bf16 (wo^T)
  unsigned short* qkv = (unsigned short*)(ws + 16777216);   // 3 x [32][2048][64] bf16
  unsigned short* ctx = (unsigned short*)(ws + 41943040);   // [4096][1024] bf16
  float*          btab = (float*)(ws + 50331648);           // [16][4095] fp32

  k_cvt<<<4096, 256, 0, stream>>>(hs, hsb, 1048576);
  k_tc<<<dim3(16, 16), 256, 0, stream>>>(wq, wt, 1024, 1024);
  k_tc<<<dim3(16, 16), 256, 0, stream>>>(wk, wt + 1048576, 1024, 1024);
  k_tc<<<dim3(16, 16), 256, 0, stream>>>(wv, wt + 2097152, 1024, 1024);
  k_tc<<<dim3(16, 16), 256, 0, stream>>>(wo, wot, 1024, 1024);
  k_bias<<<256, 256, 0, stream>>>(re, btab);

  k_gemm<0><<<dim3(24, 32), 256, 0, stream>>>(hsb, wt, qkv, 4096, 3072, 1024);
  k_attn<<<dim3(16, 32), 512, 0, stream>>>(qkv, btab, ctx);
  k_gemm<1><<<dim3(8, 32), 256, 0, stream>>>(ctx, wot, d_out, 4096, 1024, 1024);
}

// Round 2
// 161.701 us; speedup vs baseline: 1.1714x; 1.1714x over previous
//
#include <hip/hip_runtime.h>

// ---------------------------------------------------------------------------
// T5Attention forward: out = (softmax(Q K^T + bias) V) Wo
// B=2, S=2048, D=1024, H=16, DK=64, buckets=32, max_dist=128
// bf16 MFMA (16x16x32) everywhere, fp32 accumulate.
// r2: swapped QK^T (lane-local softmax), pre-transposed V (k_vt) staged via
//     global_load_lds, far-tile constant bias, defer-max, cvt_pk P-pack.
// ---------------------------------------------------------------------------

typedef __attribute__((ext_vector_type(8)))  unsigned short u16x8;
typedef __attribute__((ext_vector_type(4)))  unsigned short u16x4;
typedef __attribute__((ext_vector_type(8)))  __bf16         bf16x8;
typedef __attribute__((ext_vector_type(4)))  float          f32x4;

#define GLOBAL_AS __attribute__((address_space(1)))
#define LDS_AS    __attribute__((address_space(3)))

static __device__ inline f32x4 MFMA(u16x8 a, u16x8 b, f32x4 c) {
  return __builtin_amdgcn_mfma_f32_16x16x32_bf16(
      __builtin_bit_cast(bf16x8, a), __builtin_bit_cast(bf16x8, b), c, 0, 0, 0);
}

static __device__ inline void gload16(const void* g, void* l) {
  __builtin_amdgcn_global_load_lds((const GLOBAL_AS unsigned int*)g,
                                   (LDS_AS unsigned int*)l, 16, 0, 0);
}

// float -> bf16 bits, round-to-nearest-even
static __device__ inline unsigned short f2bf(float x) {
  unsigned int u = __builtin_bit_cast(unsigned int, x);
  u = (u + 0x7FFFu + ((u >> 16) & 1u)) >> 16;
  return (unsigned short)u;
}

// packed f32x2 -> bf16x2 (RNE), one instruction
static __device__ inline unsigned int cvtpk(float lo, float hi) {
  unsigned int r;
  asm volatile("v_cvt_pk_bf16_f32 %0, %1, %2" : "=v"(r) : "v"(lo), "v"(hi));
  return r;
}

// ---------------------------------------------------------------------------
// prep: fp32 -> bf16 convert (vectorized)
__global__ void k_cvt(const float* __restrict__ src, unsigned short* __restrict__ dst, int n4) {
  int i = blockIdx.x * blockDim.x + threadIdx.x;
  if (i >= n4) return;
  float4 v = *(const float4*)(src + (size_t)i * 4);
  u16x4 o;
  o[0] = f2bf(v.x); o[1] = f2bf(v.y); o[2] = f2bf(v.z); o[3] = f2bf(v.w);
  *(u16x4*)(dst + (size_t)i * 4) = o;
}

// prep: transpose+convert  src fp32 [K][N] row-major -> dst bf16 [N][K] row-major
__global__ __launch_bounds__(256) void k_tc(const float* __restrict__ src,
                                            unsigned short* __restrict__ dst,
                                            int K, int N) {
  __shared__ float tile[64][65];
  int k0 = blockIdx.y << 6, n0 = blockIdx.x << 6;
  int t = threadIdx.x;
  int rr = t >> 4, cc = (t & 15) << 2;
#pragma unroll
  for (int j = 0; j < 4; j++) {
    float4 v = *(const float4*)(src + (size_t)(k0 + rr + j * 16) * N + n0 + cc);
    tile[rr + j * 16][cc + 0] = v.x;
    tile[rr + j * 16][cc + 1] = v.y;
    tile[rr + j * 16][cc + 2] = v.z;
    tile[rr + j * 16][cc + 3] = v.w;
  }
  __syncthreads();
#pragma unroll
  for (int j = 0; j < 4; j++) {
    int n = rr + j * 16;
    u16x4 o;
    o[0] = f2bf(tile[cc + 0][n]);
    o[1] = f2bf(tile[cc + 1][n]);
    o[2] = f2bf(tile[cc + 2][n]);
    o[3] = f2bf(tile[cc + 3][n]);
    *(u16x4*)(dst + (size_t)(n0 + n) * K + k0 + cc) = o;
  }
}

// prep: bf16 transpose of V planes: [plane][s][d=64] -> [plane][d][s=2048]
__global__ __launch_bounds__(256) void k_vt(const unsigned short* __restrict__ v,
                                            unsigned short* __restrict__ vt) {
  __shared__ unsigned short tile[64][65];
  int plane = blockIdx.y, s0 = blockIdx.x << 6;
  const unsigned short* src = v + (size_t)plane * 131072;
  unsigned short* dst = vt + (size_t)plane * 131072;
  int t = threadIdx.x;
  int r = t & 63, cs = t >> 6;   // row s0+r, col segment cs*16
  u16x8 a = *(const u16x8*)(src + (size_t)(s0 + r) * 64 + cs * 16);
  u16x8 bqq = *(const u16x8*)(src + (size_t)(s0 + r) * 64 + cs * 16 + 8);
#pragma unroll
  for (int j = 0; j < 8; j++) { tile[r][cs * 16 + j] = a[j]; tile[r][cs * 16 + 8 + j] = bqq[j]; }
  __syncthreads();
  u16x8 o1, o2;
#pragma unroll
  for (int j = 0; j < 8; j++) { o1[j] = tile[cs * 16 + j][r]; o2[j] = tile[cs * 16 + 8 + j][r]; }
  *(u16x8*)(dst + (size_t)r * 2048 + s0 + cs * 16) = o1;
  *(u16x8*)(dst + (size_t)r * 2048 + s0 + cs * 16 + 8) = o2;
}

// prep: bias table  btab[h*4095 + (rel_pos+2047)] = rel_emb[bucket(rel_pos)][h]
__global__ void k_bias(const float* __restrict__ rel_emb, float* __restrict__ btab) {
  int i = blockIdx.x * blockDim.x + threadIdx.x;
  if (i >= 16 * 4095) return;
  int h = i / 4095;
  int rp = i % 4095 - 2047;          // rel_pos = key - query
  int rb = rp > 0 ? 16 : 0;
  int arp = rp < 0 ? -rp : rp;
  int v;
  if (arp < 8) {
    v = arp;
  } else {
    float t = logf((float)arp * 0.125f);
    t = t / 2.772588722239781f;      // log(128/8) in f32
    t = t * 8.0f;
    v = 8 + (int)t;
    if (v > 15) v = 15;
  }
  btab[i] = rel_emb[(rb + v) * 16 + h];
}

// ---------------------------------------------------------------------------
// GEMM: C[M,N] = A[M,K](bf16) * Bt[N,K](bf16, pre-transposed)
// 128x128 tile, BK=64, 4 waves (2x2 of 64x64), 16x16x32 MFMA.
// EPI=0: scatter bf16 into qkv planes [which][b,h,s,d]; EPI=1: fp32 row-major out.
template <int EPI>
__global__ __launch_bounds__(256) void k_gemm(const unsigned short* __restrict__ A,
                                              const unsigned short* __restrict__ Bt,
                                              void* __restrict__ outp,
                                              int M, int N, int K) {
  __shared__ __attribute__((aligned(16))) char smem[32768];
  const int tid = threadIdx.x;
  const int lane = tid & 63, w = tid >> 6;
  const int l15 = lane & 15, g = lane >> 4;
  const int wr = w >> 1, wc = w & 1;
  const int bm0 = blockIdx.y << 7, bn0 = blockIdx.x << 7;

  const char* Ag = (const char*)A + (size_t)bm0 * K * 2;
  const char* Bg = (const char*)Bt + (size_t)bn0 * K * 2;

  f32x4 acc[4][4];
#pragma unroll
  for (int i = 0; i < 4; i++)
#pragma unroll
    for (int j = 0; j < 4; j++) acc[i][j] = (f32x4)0.0f;

  const int rowA = wr * 64 + l15;
  const int rowB = wc * 64 + l15;
  const int swz = (l15 & 7) << 4;

  for (int kt = 0; kt < K; kt += 64) {
#pragma unroll
    for (int j = 0; j < 4; j++) {
      int idx = ((j * 4 + w) << 10) + (lane << 4);
      int row = idx >> 7;
      int gs = (idx >> 4) & 7;
      size_t co = (size_t)row * (K * 2) + kt * 2 + ((gs ^ (row & 7)) << 4);
      gload16(Ag + co, smem + ((j * 4 + w) << 10));
      gload16(Bg + co, smem + 16384 + ((j * 4 + w) << 10));
    }
    __syncthreads();
#pragma unroll
    for (int kk = 0; kk < 2; kk++) {
      const int cp = ((kk << 6) + (g << 4)) ^ swz;
      u16x8 af[4], bfv[4];
#pragma unroll
      for (int mt = 0; mt < 4; mt++)
        af[mt] = *(const u16x8*)(smem + ((rowA + mt * 16) << 7) + cp);
#pragma unroll
      for (int nt = 0; nt < 4; nt++)
        bfv[nt] = *(const u16x8*)(smem + 16384 + ((rowB + nt * 16) << 7) + cp);
#pragma unroll
      for (int mt = 0; mt < 4; mt++)
#pragma unroll
        for (int nt = 0; nt < 4; nt++)
          acc[mt][nt] = MFMA(af[mt], bfv[nt], acc[mt][nt]);
    }
    __syncthreads();
  }

#pragma unroll
  for (int mt = 0; mt < 4; mt++) {
#pragma unroll
    for (int nt = 0; nt < 4; nt++) {
#pragma unroll
      for (int r = 0; r < 4; r++) {
        int m = bm0 + wr * 64 + mt * 16 + g * 4 + r;
        int n = bn0 + wc * 64 + nt * 16 + l15;
        float val = acc[mt][nt][r];
        if (EPI == 0) {
          int which = n >> 10;
          int hh = (n >> 6) & 15;
          int d = n & 63;
          int bb = m >> 11, s = m & 2047;
          unsigned short* o = (unsigned short*)outp;
          o[(size_t)which * 4194304 + ((size_t)((bb * 16 + hh) * 2048 + s)) * 64 + d] = f2bf(val);
        } else {
          ((float*)outp)[(size_t)m * N + n] = val;
        }
      }
    }
  }
}

// ---------------------------------------------------------------------------
// Flash attention. Grid: (S/128, B*H). Block: 512 thr = 8 waves; wave = 16 q rows.
// qkv: q,k planes [B*H][2048][64] bf16. vtg: V^T planes [B*H][64][2048] bf16.
// Swapped QK^T: S^T = MFMA(K_frag, Q_frag) -> lane holds 16 scores for q=l15.
__global__ __launch_bounds__(512) void k_attn(const unsigned short* __restrict__ qkv,
                                              const unsigned short* __restrict__ vtg,
                                              const float* __restrict__ btab,
                                              unsigned short* __restrict__ ctx) {
  __shared__ __attribute__((aligned(16))) char smem[32768]; // K:0..8K, Vt:8K..16K, P:16K..32K
  const int tid = threadIdx.x;
  const int lane = tid & 63, w = tid >> 6;
  const int l15 = lane & 15, g = lane >> 4;
  const int plane = blockIdx.y;
  const int h = plane & 15, b = plane >> 4;
  const int q0 = (blockIdx.x << 7) + (w << 4);

  const unsigned short* Qp = qkv + (size_t)plane * 131072;
  const unsigned short* Kp = qkv + 4194304 + (size_t)plane * 131072;
  const unsigned short* Vt = vtg + (size_t)plane * 131072;

  u16x8 qa[2];
#pragma unroll
  for (int kk = 0; kk < 2; kk++)
    qa[kk] = *(const u16x8*)(Qp + (size_t)(q0 + l15) * 64 + kk * 32 + g * 8);

  float m_r = -1e30f, l_r = 0.0f;
  f32x4 oacc[4];
#pragma unroll
  for (int t = 0; t < 4; t++) oacc[t] = (f32x4)0.0f;

  const float* brow = btab + h * 4095 + 2047 - q0;
  const float cpos = btab[h * 4095 + 2047 + 1024];
  const float cneg = btab[h * 4095 + 2047 - 1024];
  const float LOG2E = 1.4426950408889634f;

  // staging source addresses (pre-swizzled for linear global_load_lds dest)
  const int srow = tid >> 3, sgs = tid & 7;
  const char* Ksrc = (const char*)Kp + (size_t)srow * 128 + ((sgs ^ (srow & 7)) << 4);
  const char* Vsrc = (const char*)Vt + (size_t)srow * 4096 + ((sgs ^ (srow & 7)) << 4);

  for (int kv = 0; kv < 2048; kv += 64) {
    gload16(Ksrc + (size_t)kv * 128, smem + (w << 10));            // K tile [64 keys][64 d]
    gload16(Vsrc + (size_t)kv * 2, smem + 8192 + (w << 10));       // V^T tile [64 d][64 keys]
    __syncthreads();

    // S^T = K Q^T : lane holds S^T[key = nt*16 + g*4 + r][q = q0 + l15]
    f32x4 s[4];
#pragma unroll
    for (int nt = 0; nt < 4; nt++) {
      int keyr = nt * 16 + l15;
      int sw = (keyr & 7) << 4;
      u16x8 kb0 = *(const u16x8*)(smem + (keyr << 7) + ((g << 4) ^ sw));
      u16x8 kb1 = *(const u16x8*)(smem + (keyr << 7) + ((64 + (g << 4)) ^ sw));
      f32x4 z = (f32x4)0.0f;
      z = MFMA(kb0, qa[0], z);
      z = MFMA(kb1, qa[1], z);
      s[nt] = z;
    }

    // + position bias (rel = key - q); far tiles have saturated (constant) bucket
    int delta = kv - q0;
    if (delta >= 112 || delta <= -160) {
      float c = delta > 0 ? cpos : cneg;
#pragma unroll
      for (int nt = 0; nt < 4; nt++)
#pragma unroll
        for (int r = 0; r < 4; r++) s[nt][r] += c;
    } else {
      const float* bp = brow + kv + (g << 2) - l15;
#pragma unroll
      for (int nt = 0; nt < 4; nt++)
#pragma unroll
        for (int r = 0; r < 4; r++) s[nt][r] += bp[nt * 16 + r];
    }

    // online softmax, lane-local row (q = l15); reduce across g (2 shfls)
    float mloc = s[0][0];
#pragma unroll
    for (int nt = 0; nt < 4; nt++)
#pragma unroll
      for (int r = 0; r < 4; r++) mloc = fmaxf(mloc, s[nt][r]);
    float mx = fmaxf(mloc, __shfl_xor(mloc, 16));
    mx = fmaxf(mx, __shfl_xor(mx, 32));

    if (!__all(mx <= m_r + 8.0f)) {   // defer-max: skip rescale when growth small
      float mnew = fmaxf(m_r, mx);
      float alpha = exp2f((m_r - mnew) * LOG2E);
      m_r = mnew;
      l_r *= alpha;
      float a4[4];
#pragma unroll
      for (int r = 0; r < 4; r++) a4[r] = __shfl(alpha, (g << 2) + r);
#pragma unroll
      for (int t = 0; t < 4; t++) {
        f32x4 o = oacc[t];
        o[0] *= a4[0]; o[1] *= a4[1]; o[2] *= a4[2]; o[3] *= a4[3];
        oacc[t] = o;
      }
    }

    float su = 0.0f;
#pragma unroll
    for (int nt = 0; nt < 4; nt++)
#pragma unroll
      for (int r = 0; r < 4; r++) {
        s[nt][r] = exp2f((s[nt][r] - m_r) * LOG2E);
        su += s[nt][r];
      }
    su += __shfl_xor(su, 16);
    su += __shfl_xor(su, 32);
    l_r += su;

    // P -> per-wave LDS [16 q][64 key] bf16, 8B packed writes, XOR-swizzled
    char* Pb = smem + 16384 + (w << 11);
    const int pswz = (l15 & 7) << 4;
#pragma unroll
    for (int nt = 0; nt < 4; nt++) {
      uint2 pw;
      pw.x = cvtpk(s[nt][0], s[nt][1]);
      pw.y = cvtpk(s[nt][2], s[nt][3]);
      *(uint2*)(Pb + (l15 << 7) + (((nt << 5) + (g << 3)) ^ pswz)) = pw;
    }
    asm volatile("s_waitcnt lgkmcnt(0)" ::: "memory");
    __builtin_amdgcn_sched_barrier(0);

    u16x8 pa[2];
#pragma unroll
    for (int kk = 0; kk < 2; kk++)
      pa[kk] = *(const u16x8*)(Pb + (l15 << 7) + (((kk << 6) + (g << 4)) ^ pswz));

    // O += P V   (A = P[q][key], B = V^T rows as B[k][d])
#pragma unroll
    for (int t = 0; t < 4; t++) {
      int d = t * 16 + l15;
      int sw = (d & 7) << 4;
      u16x8 vb0 = *(const u16x8*)(smem + 8192 + (d << 7) + ((g << 4) ^ sw));
      u16x8 vb1 = *(const u16x8*)(smem + 8192 + (d << 7) + ((64 + (g << 4)) ^ sw));
      oacc[t] = MFMA(pa[0], vb0, oacc[t]);
      oacc[t] = MFMA(pa[1], vb1, oacc[t]);
    }
    __syncthreads();
  }

  float invl = 1.0f / l_r;
#pragma unroll
  for (int r = 0; r < 4; r++) {
    float inv = __shfl(invl, (g << 2) + r);
    size_t rowoff = ((size_t)(b * 2048 + q0 + (g << 2) + r) << 10) + h * 64;
#pragma unroll
    for (int t = 0; t < 4; t++)
      ctx[rowoff + t * 16 + l15] = f2bf(oacc[t][r] * inv);
  }
}

// ---------------------------------------------------------------------------
extern "C" void kernel_launch(void* const* d_in, const int* in_sizes, int n_in,
                              void* d_out, int out_size, void* d_ws, size_t ws_size,
                              hipStream_t stream) {
  const float* hs = (const float*)d_in[0];
  const float* wq = (const float*)d_in[1];
  const float* wk = (const float*)d_in[2];
  const float* wv = (const float*)d_in[3];
  const float* wo = (const float*)d_in[4];
  const float* re = (const float*)d_in[5];

  if (ws_size < 50593728u) return;

  char* ws = (char*)d_ws;
  unsigned short* hsb = (unsigned short*)(ws);              // [4096][1024] bf16
  unsigned short* wt  = (unsigned short*)(ws + 8388608);    // [3072][1024] bf16 (wq,wk,wv ^T)
  unsigned short* wot = (unsigned short*)(ws + 14680064);   // [1024][1024] bf16 (wo^T)
  unsigned short* qkv = (unsigned short*)(ws + 16777216);   // 3 x [32][2048][64] bf16
  unsigned short* ctx = (unsigned short*)(ws + 41943040);   // [4096][1024] bf16
  float*          btab = (float*)(ws + 50331648);           // [16][4095] fp32
  // vtg overlays hsb (dead after k_gemm<0>): [32][64][2048] bf16 = 8.4 MB
  unsigned short* vtg = (unsigned short*)(ws);

  k_cvt<<<4096, 256, 0, stream>>>(hs, hsb, 1048576);
  k_tc<<<dim3(16, 16), 256, 0, stream>>>(wq, wt, 1024, 1024);
  k_tc<<<dim3(16, 16), 256, 0, stream>>>(wk, wt + 1048576, 1024, 1024);
  k_tc<<<dim3(16, 16), 256, 0, stream>>>(wv, wt + 2097152, 1024, 1024);
  k_tc<<<dim3(16, 16), 256, 0, stream>>>(wo, wot, 1024, 1024);
  k_bias<<<256, 256, 0, stream>>>(re, btab);

  k_gemm<0><<<dim3(24, 32), 256, 0, stream>>>(hsb, wt, qkv, 4096, 3072, 1024);
  k_vt<<<dim3(32, 32), 256, 0, stream>>>(qkv + 2 * 4194304, vtg);
  k_attn<<<dim3(16, 32), 512, 0, stream>>>(qkv, vtg, btab, ctx);
  k_gemm<1><<<dim3(8, 32), 256, 0, stream>>>(ctx, wot, d_out, 4096, 1024, 1024);
}

// Round 3
// 157.461 us; speedup vs baseline: 1.2029x; 1.0269x over previous
//
#include <hip/hip_runtime.h>

// ---------------------------------------------------------------------------
// T5Attention forward: out = (softmax(Q K^T + bias) V) Wo
// B=2, S=2048, D=1024, H=16, DK=64, buckets=32, max_dist=128
// bf16 MFMA (16x16x32), fp32 accumulate.
// r3: in-register P transpose (cvt_pk + permlane32/16_swap), MFMA l-sum,
//     bias folded into exp, K/V double-buffer w/ early stage, 4-wave blocks,
//     XCD-chunked plane swizzle, setprio.
// ---------------------------------------------------------------------------

typedef __attribute__((ext_vector_type(8)))  unsigned short u16x8;
typedef __attribute__((ext_vector_type(4)))  unsigned short u16x4;
typedef __attribute__((ext_vector_type(8)))  __bf16         bf16x8;
typedef __attribute__((ext_vector_type(4)))  float          f32x4;
typedef __attribute__((ext_vector_type(4)))  unsigned int   u32x4;

#define GLOBAL_AS __attribute__((address_space(1)))
#define LDS_AS    __attribute__((address_space(3)))

static __device__ inline f32x4 MFMA(u16x8 a, u16x8 b, f32x4 c) {
  return __builtin_amdgcn_mfma_f32_16x16x32_bf16(
      __builtin_bit_cast(bf16x8, a), __builtin_bit_cast(bf16x8, b), c, 0, 0, 0);
}

static __device__ inline void gload16(const void* g, void* l) {
  __builtin_amdgcn_global_load_lds((const GLOBAL_AS unsigned int*)g,
                                   (LDS_AS unsigned int*)l, 16, 0, 0);
}

// float -> bf16 bits, round-to-nearest-even
static __device__ inline unsigned short f2bf(float x) {
  unsigned int u = __builtin_bit_cast(unsigned int, x);
  u = (u + 0x7FFFu + ((u >> 16) & 1u)) >> 16;
  return (unsigned short)u;
}

// packed f32x2 -> bf16x2, one instruction
static __device__ inline unsigned int cvtpk(float lo, float hi) {
  unsigned int r;
  asm volatile("v_cvt_pk_bf16_f32 %0, %1, %2" : "=v"(r) : "v"(lo), "v"(hi));
  return r;
}

// ---------------------------------------------------------------------------
// prep: fp32 -> bf16 convert (vectorized)
__global__ void k_cvt(const float* __restrict__ src, unsigned short* __restrict__ dst, int n4) {
  int i = blockIdx.x * blockDim.x + threadIdx.x;
  if (i >= n4) return;
  float4 v = *(const float4*)(src + (size_t)i * 4);
  u16x4 o;
  o[0] = f2bf(v.x); o[1] = f2bf(v.y); o[2] = f2bf(v.z); o[3] = f2bf(v.w);
  *(u16x4*)(dst + (size_t)i * 4) = o;
}

// prep: transpose+convert  src fp32 [K][N] row-major -> dst bf16 [N][K] row-major
__global__ __launch_bounds__(256) void k_tc(const float* __restrict__ src,
                                            unsigned short* __restrict__ dst,
                                            int K, int N) {
  __shared__ float tile[64][65];
  int k0 = blockIdx.y << 6, n0 = blockIdx.x << 6;
  int t = threadIdx.x;
  int rr = t >> 4, cc = (t & 15) << 2;
#pragma unroll
  for (int j = 0; j < 4; j++) {
    float4 v = *(const float4*)(src + (size_t)(k0 + rr + j * 16) * N + n0 + cc);
    tile[rr + j * 16][cc + 0] = v.x;
    tile[rr + j * 16][cc + 1] = v.y;
    tile[rr + j * 16][cc + 2] = v.z;
    tile[rr + j * 16][cc + 3] = v.w;
  }
  __syncthreads();
#pragma unroll
  for (int j = 0; j < 4; j++) {
    int n = rr + j * 16;
    u16x4 o;
    o[0] = f2bf(tile[cc + 0][n]);
    o[1] = f2bf(tile[cc + 1][n]);
    o[2] = f2bf(tile[cc + 2][n]);
    o[3] = f2bf(tile[cc + 3][n]);
    *(u16x4*)(dst + (size_t)(n0 + n) * K + k0 + cc) = o;
  }
}

// prep: bf16 transpose of V planes: [plane][s][d=64] -> [plane][d][s=2048]
__global__ __launch_bounds__(256) void k_vt(const unsigned short* __restrict__ v,
                                            unsigned short* __restrict__ vt) {
  __shared__ unsigned short tile[64][65];
  int plane = blockIdx.y, s0 = blockIdx.x << 6;
  const unsigned short* src = v + (size_t)plane * 131072;
  unsigned short* dst = vt + (size_t)plane * 131072;
  int t = threadIdx.x;
  int r = t & 63, cs = t >> 6;
  u16x8 a = *(const u16x8*)(src + (size_t)(s0 + r) * 64 + cs * 16);
  u16x8 bqq = *(const u16x8*)(src + (size_t)(s0 + r) * 64 + cs * 16 + 8);
#pragma unroll
  for (int j = 0; j < 8; j++) { tile[r][cs * 16 + j] = a[j]; tile[r][cs * 16 + 8 + j] = bqq[j]; }
  __syncthreads();
  u16x8 o1, o2;
#pragma unroll
  for (int j = 0; j < 8; j++) { o1[j] = tile[cs * 16 + j][r]; o2[j] = tile[cs * 16 + 8 + j][r]; }
  *(u16x8*)(dst + (size_t)r * 2048 + s0 + cs * 16) = o1;
  *(u16x8*)(dst + (size_t)r * 2048 + s0 + cs * 16 + 8) = o2;
}

// prep: bias table  btab[h*4095 + (rel_pos+2047)] = rel_emb[bucket(rel_pos)][h]
__global__ void k_bias(const float* __restrict__ rel_emb, float* __restrict__ btab) {
  int i = blockIdx.x * blockDim.x + threadIdx.x;
  if (i >= 16 * 4095) return;
  int h = i / 4095;
  int rp = i % 4095 - 2047;
  int rb = rp > 0 ? 16 : 0;
  int arp = rp < 0 ? -rp : rp;
  int v;
  if (arp < 8) {
    v = arp;
  } else {
    float t = logf((float)arp * 0.125f);
    t = t / 2.772588722239781f;
    t = t * 8.0f;
    v = 8 + (int)t;
    if (v > 15) v = 15;
  }
  btab[i] = rel_emb[(rb + v) * 16 + h];
}

// ---------------------------------------------------------------------------
// GEMM: C[M,N] = A[M,K](bf16) * Bt[N,K](bf16, pre-transposed)
template <int EPI>
__global__ __launch_bounds__(256) void k_gemm(const unsigned short* __restrict__ A,
                                              const unsigned short* __restrict__ Bt,
                                              void* __restrict__ outp,
                                              int M, int N, int K) {
  __shared__ __attribute__((aligned(16))) char smem[32768];
  const int tid = threadIdx.x;
  const int lane = tid & 63, w = tid >> 6;
  const int l15 = lane & 15, g = lane >> 4;
  const int wr = w >> 1, wc = w & 1;
  const int bm0 = blockIdx.y << 7, bn0 = blockIdx.x << 7;

  const char* Ag = (const char*)A + (size_t)bm0 * K * 2;
  const char* Bg = (const char*)Bt + (size_t)bn0 * K * 2;

  f32x4 acc[4][4];
#pragma unroll
  for (int i = 0; i < 4; i++)
#pragma unroll
    for (int j = 0; j < 4; j++) acc[i][j] = (f32x4)0.0f;

  const int rowA = wr * 64 + l15;
  const int rowB = wc * 64 + l15;
  const int swz = (l15 & 7) << 4;

  for (int kt = 0; kt < K; kt += 64) {
#pragma unroll
    for (int j = 0; j < 4; j++) {
      int idx = ((j * 4 + w) << 10) + (lane << 4);
      int row = idx >> 7;
      int gs = (idx >> 4) & 7;
      size_t co = (size_t)row * (K * 2) + kt * 2 + ((gs ^ (row & 7)) << 4);
      gload16(Ag + co, smem + ((j * 4 + w) << 10));
      gload16(Bg + co, smem + 16384 + ((j * 4 + w) << 10));
    }
    __syncthreads();
#pragma unroll
    for (int kk = 0; kk < 2; kk++) {
      const int cp = ((kk << 6) + (g << 4)) ^ swz;
      u16x8 af[4], bfv[4];
#pragma unroll
      for (int mt = 0; mt < 4; mt++)
        af[mt] = *(const u16x8*)(smem + ((rowA + mt * 16) << 7) + cp);
#pragma unroll
      for (int nt = 0; nt < 4; nt++)
        bfv[nt] = *(const u16x8*)(smem + 16384 + ((rowB + nt * 16) << 7) + cp);
#pragma unroll
      for (int mt = 0; mt < 4; mt++)
#pragma unroll
        for (int nt = 0; nt < 4; nt++)
          acc[mt][nt] = MFMA(af[mt], bfv[nt], acc[mt][nt]);
    }
    __syncthreads();
  }

#pragma unroll
  for (int mt = 0; mt < 4; mt++) {
#pragma unroll
    for (int nt = 0; nt < 4; nt++) {
#pragma unroll
      for (int r = 0; r < 4; r++) {
        int m = bm0 + wr * 64 + mt * 16 + g * 4 + r;
        int n = bn0 + wc * 64 + nt * 16 + l15;
        float val = acc[mt][nt][r];
        if (EPI == 0) {
          int which = n >> 10;
          int hh = (n >> 6) & 15;
          int d = n & 63;
          int bb = m >> 11, s = m & 2047;
          unsigned short* o = (unsigned short*)outp;
          o[(size_t)which * 4194304 + ((size_t)((bb * 16 + hh) * 2048 + s)) * 64 + d] = f2bf(val);
        } else {
          ((float*)outp)[(size_t)m * N + n] = val;
        }
      }
    }
  }
}

// ---------------------------------------------------------------------------
// Flash attention. Grid: 1024 blocks (plane-major w/ XCD chunk swizzle).
// Block: 256 thr = 4 waves; wave = 16 q rows. Per-tile: swapped QK^T,
// in-register softmax + P transpose via permlane swaps, PV + MFMA l-sum.
__global__ __launch_bounds__(256) void k_attn(const unsigned short* __restrict__ qkv,
                                              const unsigned short* __restrict__ vtg,
                                              const float* __restrict__ btab,
                                              unsigned short* __restrict__ ctx) {
  __shared__ __attribute__((aligned(16))) char smem[32768]; // 2 bufs x (K 8K + V 8K)
  const int tid = threadIdx.x;
  const int lane = tid & 63, w = tid >> 6;
  const int l15 = lane & 15, g = lane >> 4;

  // XCD-chunked swizzle: consecutive wg on one XCD share a plane
  const int wg = ((blockIdx.x & 7) << 7) + (blockIdx.x >> 3);
  const int plane = wg >> 5, qb = wg & 31;
  const int h = plane & 15, b = plane >> 4;
  const int q0 = (qb << 6) + (w << 4);

  const unsigned short* Qp = qkv + (size_t)plane * 131072;
  const unsigned short* Kp = qkv + 4194304 + (size_t)plane * 131072;
  const unsigned short* Vt = vtg + (size_t)plane * 131072;

  u16x8 qa[2];
#pragma unroll
  for (int kk = 0; kk < 2; kk++)
    qa[kk] = *(const u16x8*)(Qp + (size_t)(q0 + l15) * 64 + kk * 32 + g * 8);

  float m_r = -1e30f;
  f32x4 oacc[4], lacc;
#pragma unroll
  for (int t = 0; t < 4; t++) oacc[t] = (f32x4)0.0f;
  lacc = (f32x4)0.0f;

  const float* brow = btab + h * 4095 + 2047 - q0;
  const float cpos = btab[h * 4095 + 2047 + 1024];
  const float cneg = btab[h * 4095 + 2047 - 1024];
  const float LOG2E = 1.4426950408889634f;

  u16x8 ones;
  {
    u32x4 ov = {0x3F803F80u, 0x3F803F80u, 0x3F803F80u, 0x3F803F80u};
    ones = __builtin_bit_cast(u16x8, ov);
  }

  // staging source addrs (pre-swizzled, linear LDS dest)
  const int srow = (w << 3) + (lane >> 3);   // 0..31
  const int soff = ((lane & 7) ^ (srow & 7)) << 4;
  const char* Ksrc = (const char*)Kp + (size_t)srow * 128 + soff;
  const char* Vsrc = (const char*)Vt + (size_t)srow * 4096 + soff;

  auto STAGE = [&](int t, int bsel) {
    char* sb = smem + (bsel << 14) + (w << 10);
    const char* ka = Ksrc + (size_t)t * 8192;
    gload16(ka, sb);
    gload16(ka + 4096, sb + 4096);
    const char* va = Vsrc + (size_t)t * 128;
    gload16(va, sb + 8192);
    gload16(va + 131072, sb + 12288);
  };

  STAGE(0, 0);
  __syncthreads();

  for (int t = 0; t < 32; ++t) {
    const int c = t & 1;
    if (t < 31) STAGE(t + 1, c ^ 1);
    const char* kb = smem + (c << 14);
    const char* vb = kb + 8192;
    const int kv = t << 6;

    // S^T = K Q^T : lane holds S^T[key = nt*16 + g*4 + r][q = q0 + l15]
    f32x4 s[4];
    __builtin_amdgcn_s_setprio(1);
#pragma unroll
    for (int nt = 0; nt < 4; nt++) {
      int keyr = nt * 16 + l15;
      int sw = (keyr & 7) << 4;
      u16x8 kb0 = *(const u16x8*)(kb + (keyr << 7) + ((g << 4) ^ sw));
      u16x8 kb1 = *(const u16x8*)(kb + (keyr << 7) + ((64 + (g << 4)) ^ sw));
      f32x4 z = (f32x4)0.0f;
      z = MFMA(kb0, qa[0], z);
      z = MFMA(kb1, qa[1], z);
      s[nt] = z;
    }
    __builtin_amdgcn_s_setprio(0);

    // bias: far tiles -> wave-uniform constant folded into exp arg
    int delta = kv - q0;
    float cb;
    if (delta >= 112 || delta <= -160) {
      cb = delta > 0 ? cpos : cneg;
    } else {
      cb = 0.0f;
      const float* bp = brow + kv + (g << 2) - l15;
#pragma unroll
      for (int nt = 0; nt < 4; nt++)
#pragma unroll
        for (int r = 0; r < 4; r++) s[nt][r] += bp[nt * 16 + r];
    }

    // local max over this lane's 16 scores (partial row max)
    float m1 = fmaxf(fmaxf(s[0][0], s[0][1]), s[0][2]);
    float m2 = fmaxf(fmaxf(s[0][3], s[1][0]), s[1][1]);
    float m3 = fmaxf(fmaxf(s[1][2], s[1][3]), s[2][0]);
    float m4 = fmaxf(fmaxf(s[2][1], s[2][2]), s[2][3]);
    float m5 = fmaxf(fmaxf(s[3][0], s[3][1]), s[3][2]);
    float mloc = fmaxf(fmaxf(fmaxf(m1, m2), fmaxf(m3, m4)), fmaxf(m5, s[3][3]));

    if (!__all(mloc + cb <= m_r + 8.0f)) {   // defer-max
      float mxrow = fmaxf(mloc, __shfl_xor(mloc, 16));
      mxrow = fmaxf(mxrow, __shfl_xor(mxrow, 32));
      float mnew = fmaxf(m_r, mxrow + cb);
      float alpha = exp2f((m_r - mnew) * LOG2E);
      m_r = mnew;
      float a4[4];
#pragma unroll
      for (int r = 0; r < 4; r++) a4[r] = __shfl(alpha, (g << 2) + r);
#pragma unroll
      for (int tt = 0; tt < 4; tt++) {
        f32x4 o = oacc[tt];
        o[0] *= a4[0]; o[1] *= a4[1]; o[2] *= a4[2]; o[3] *= a4[3];
        oacc[tt] = o;
      }
      lacc[0] *= a4[0]; lacc[1] *= a4[1]; lacc[2] *= a4[2]; lacc[3] *= a4[3];
    }

    // P = exp2((s + cb - m) * log2e), bias folded into eb
    float eb = (cb - m_r) * LOG2E;
#pragma unroll
    for (int nt = 0; nt < 4; nt++)
#pragma unroll
      for (int r = 0; r < 4; r++)
        s[nt][r] = __builtin_amdgcn_exp2f(fmaf(s[nt][r], LOG2E, eb));

    // pack P -> bf16 pairs, then permlane-swap into PV A-fragments
    unsigned int wpk[4][2];
#pragma unroll
    for (int nt = 0; nt < 4; nt++) {
      wpk[nt][0] = cvtpk(s[nt][0], s[nt][1]);
      wpk[nt][1] = cvtpk(s[nt][2], s[nt][3]);
    }
    u16x8 pa[2];
#pragma unroll
    for (int kk = 0; kk < 2; kk++) {
      unsigned int X0 = wpk[2 * kk][0], Y0 = wpk[2 * kk + 1][0];
      asm volatile("v_permlane32_swap_b32 %0, %1" : "+v"(X0), "+v"(Y0));
      asm volatile("v_permlane16_swap_b32 %0, %1" : "+v"(X0), "+v"(Y0));
      unsigned int X1 = wpk[2 * kk][1], Y1 = wpk[2 * kk + 1][1];
      asm volatile("v_permlane32_swap_b32 %0, %1" : "+v"(X1), "+v"(Y1));
      asm volatile("v_permlane16_swap_b32 %0, %1" : "+v"(X1), "+v"(Y1));
      u32x4 pw = {X0, X1, Y0, Y1};   // words w0,w1,w2,w3
      pa[kk] = __builtin_bit_cast(u16x8, pw);
    }

    // O += P V ; l += P * ones
    __builtin_amdgcn_s_setprio(1);
#pragma unroll
    for (int tt = 0; tt < 4; tt++) {
      int d = tt * 16 + l15;
      int sw = (d & 7) << 4;
      u16x8 vb0 = *(const u16x8*)(vb + (d << 7) + ((g << 4) ^ sw));
      u16x8 vb1 = *(const u16x8*)(vb + (d << 7) + ((64 + (g << 4)) ^ sw));
      oacc[tt] = MFMA(pa[0], vb0, oacc[tt]);
      oacc[tt] = MFMA(pa[1], vb1, oacc[tt]);
    }
    lacc = MFMA(pa[0], ones, lacc);
    lacc = MFMA(pa[1], ones, lacc);
    __builtin_amdgcn_s_setprio(0);

    __syncthreads();
  }

#pragma unroll
  for (int r = 0; r < 4; r++) {
    float inv = 1.0f / lacc[r];
    size_t rowoff = ((size_t)(b * 2048 + q0 + (g << 2) + r) << 10) + h * 64;
#pragma unroll
    for (int tt = 0; tt < 4; tt++)
      ctx[rowoff + tt * 16 + l15] = f2bf(oacc[tt][r] * inv);
  }
}

// ---------------------------------------------------------------------------
extern "C" void kernel_launch(void* const* d_in, const int* in_sizes, int n_in,
                              void* d_out, int out_size, void* d_ws, size_t ws_size,
                              hipStream_t stream) {
  const float* hs = (const float*)d_in[0];
  const float* wq = (const float*)d_in[1];
  const float* wk = (const float*)d_in[2];
  const float* wv = (const float*)d_in[3];
  const float* wo = (const float*)d_in[4];
  const float* re = (const float*)d_in[5];

  if (ws_size < 50593728u) return;

  char* ws = (char*)d_ws;
  unsigned short* hsb = (unsigned short*)(ws);              // [4096][1024] bf16
  unsigned short* wt  = (unsigned short*)(ws + 8388608);    // [3072][1024] bf16
  unsigned short* wot = (unsigned short*)(ws + 14680064);   // [1024][1024] bf16
  unsigned short* qkv = (unsigned short*)(ws + 16777216);   // 3 x [32][2048][64] bf16
  unsigned short* ctx = (unsigned short*)(ws + 41943040);   // [4096][1024] bf16
  float*          btab = (float*)(ws + 50331648);           // [16][4095] fp32
  unsigned short* vtg = (unsigned short*)(ws);              // overlays hsb post-GEMM

  k_cvt<<<4096, 256, 0, stream>>>(hs, hsb, 1048576);
  k_tc<<<dim3(16, 16), 256, 0, stream>>>(wq, wt, 1024, 1024);
  k_tc<<<dim3(16, 16), 256, 0, stream>>>(wk, wt + 1048576, 1024, 1024);
  k_tc<<<dim3(16, 16), 256, 0, stream>>>(wv, wt + 2097152, 1024, 1024);
  k_tc<<<dim3(16, 16), 256, 0, stream>>>(wo, wot, 1024, 1024);
  k_bias<<<256, 256, 0, stream>>>(re, btab);

  k_gemm<0><<<dim3(24, 32), 256, 0, stream>>>(hsb, wt, qkv, 4096, 3072, 1024);
  k_vt<<<dim3(32, 32), 256, 0, stream>>>(qkv + 2 * 4194304, vtg);
  k_attn<<<1024, 256, 0, stream>>>(qkv, vtg, btab, ctx);
  k_gemm<1><<<dim3(8, 32), 256, 0, stream>>>(ctx, wot, d_out, 4096, 1024, 1024);
}

// Round 7
// 155.552 us; speedup vs baseline: 1.2177x; 1.0123x over previous
//
#include <hip/hip_runtime.h>

// ---------------------------------------------------------------------------
// T5Attention forward: out = (softmax(Q K^T + bias) V) Wo
// B=2, S=2048, D=1024, H=16, DK=64, buckets=32, max_dist=128
// bf16 MFMA (16x16x32), fp32 accumulate.
// r7 = BISECT: r3 kernel (passed) + ONLY change-set (b):
//   - V^T produced by GEMM<0> epilogue (k_vt deleted)
//   - Q pre-scaled by log2e in GEMM epilogue; bias table pre-scaled
//   - softmax in log2 domain (defer-max thr 12), r3 structure otherwise
// QBLK=16/wave, grid 1024, r3 sync structure, r3 defer-max. UNCHANGED.
// ---------------------------------------------------------------------------

typedef __attribute__((ext_vector_type(8)))  unsigned short u16x8;
typedef __attribute__((ext_vector_type(4)))  unsigned short u16x4;
typedef __attribute__((ext_vector_type(8)))  __bf16         bf16x8;
typedef __attribute__((ext_vector_type(4)))  float          f32x4;
typedef __attribute__((ext_vector_type(4)))  unsigned int   u32x4;

#define GLOBAL_AS __attribute__((address_space(1)))
#define LDS_AS    __attribute__((address_space(3)))

static __device__ inline f32x4 MFMA(u16x8 a, u16x8 b, f32x4 c) {
  return __builtin_amdgcn_mfma_f32_16x16x32_bf16(
      __builtin_bit_cast(bf16x8, a), __builtin_bit_cast(bf16x8, b), c, 0, 0, 0);
}

static __device__ inline void gload16(const void* g, void* l) {
  __builtin_amdgcn_global_load_lds((const GLOBAL_AS unsigned int*)g,
                                   (LDS_AS unsigned int*)l, 16, 0, 0);
}

// float -> bf16 bits, round-to-nearest-even
static __device__ inline unsigned short f2bf(float x) {
  unsigned int u = __builtin_bit_cast(unsigned int, x);
  u = (u + 0x7FFFu + ((u >> 16) & 1u)) >> 16;
  return (unsigned short)u;
}

// packed f32x2 -> bf16x2, one instruction
static __device__ inline unsigned int cvtpk(float lo, float hi) {
  unsigned int r;
  asm volatile("v_cvt_pk_bf16_f32 %0, %1, %2" : "=v"(r) : "v"(lo), "v"(hi));
  return r;
}

#define L2E 1.4426950408889634f

// ---------------------------------------------------------------------------
// prep: fp32 -> bf16 convert (vectorized)
__global__ void k_cvt(const float* __restrict__ src, unsigned short* __restrict__ dst, int n4) {
  int i = blockIdx.x * blockDim.x + threadIdx.x;
  if (i >= n4) return;
  float4 v = *(const float4*)(src + (size_t)i * 4);
  u16x4 o;
  o[0] = f2bf(v.x); o[1] = f2bf(v.y); o[2] = f2bf(v.z); o[3] = f2bf(v.w);
  *(u16x4*)(dst + (size_t)i * 4) = o;
}

// prep: transpose+convert  src fp32 [K][N] row-major -> dst bf16 [N][K] row-major
__global__ __launch_bounds__(256) void k_tc(const float* __restrict__ src,
                                            unsigned short* __restrict__ dst,
                                            int K, int N) {
  __shared__ float tile[64][65];
  int k0 = blockIdx.y << 6, n0 = blockIdx.x << 6;
  int t = threadIdx.x;
  int rr = t >> 4, cc = (t & 15) << 2;
#pragma unroll
  for (int j = 0; j < 4; j++) {
    float4 v = *(const float4*)(src + (size_t)(k0 + rr + j * 16) * N + n0 + cc);
    tile[rr + j * 16][cc + 0] = v.x;
    tile[rr + j * 16][cc + 1] = v.y;
    tile[rr + j * 16][cc + 2] = v.z;
    tile[rr + j * 16][cc + 3] = v.w;
  }
  __syncthreads();
#pragma unroll
  for (int j = 0; j < 4; j++) {
    int n = rr + j * 16;
    u16x4 o;
    o[0] = f2bf(tile[cc + 0][n]);
    o[1] = f2bf(tile[cc + 1][n]);
    o[2] = f2bf(tile[cc + 2][n]);
    o[3] = f2bf(tile[cc + 3][n]);
    *(u16x4*)(dst + (size_t)(n0 + n) * K + k0 + cc) = o;
  }
}

// prep: bias table (pre-scaled by log2e)
// btab[h*4095 + (rel_pos+2047)] = rel_emb[bucket(rel_pos)][h] * L2E
__global__ void k_bias(const float* __restrict__ rel_emb, float* __restrict__ btab) {
  int i = blockIdx.x * blockDim.x + threadIdx.x;
  if (i >= 16 * 4095) return;
  int h = i / 4095;
  int rp = i % 4095 - 2047;
  int rb = rp > 0 ? 16 : 0;
  int arp = rp < 0 ? -rp : rp;
  int v;
  if (arp < 8) {
    v = arp;
  } else {
    float t = logf((float)arp * 0.125f);
    t = t / 2.772588722239781f;
    t = t * 8.0f;
    v = 8 + (int)t;
    if (v > 15) v = 15;
  }
  btab[i] = rel_emb[(rb + v) * 16 + h] * L2E;
}

// ---------------------------------------------------------------------------
// GEMM: C[M,N] = A[M,K](bf16) * Bt[N,K](bf16, pre-transposed)
// EPI=0: scatter into qkv planes; Q scaled by log2e; V written TRANSPOSED
//        ([plane][d][s]). EPI=1: fp32 row-major out.
template <int EPI>
__global__ __launch_bounds__(256) void k_gemm(const unsigned short* __restrict__ A,
                                              const unsigned short* __restrict__ Bt,
                                              void* __restrict__ outp,
                                              int M, int N, int K) {
  __shared__ __attribute__((aligned(16))) char smem[32768];
  const int tid = threadIdx.x;
  const int lane = tid & 63, w = tid >> 6;
  const int l15 = lane & 15, g = lane >> 4;
  const int wr = w >> 1, wc = w & 1;
  const int bm0 = blockIdx.y << 7, bn0 = blockIdx.x << 7;

  const char* Ag = (const char*)A + (size_t)bm0 * K * 2;
  const char* Bg = (const char*)Bt + (size_t)bn0 * K * 2;

  f32x4 acc[4][4];
#pragma unroll
  for (int i = 0; i < 4; i++)
#pragma unroll
    for (int j = 0; j < 4; j++) acc[i][j] = (f32x4)0.0f;

  const int rowA = wr * 64 + l15;
  const int rowB = wc * 64 + l15;
  const int swz = (l15 & 7) << 4;

  for (int kt = 0; kt < K; kt += 64) {
#pragma unroll
    for (int j = 0; j < 4; j++) {
      int idx = ((j * 4 + w) << 10) + (lane << 4);
      int row = idx >> 7;
      int gs = (idx >> 4) & 7;
      size_t co = (size_t)row * (K * 2) + kt * 2 + ((gs ^ (row & 7)) << 4);
      gload16(Ag + co, smem + ((j * 4 + w) << 10));
      gload16(Bg + co, smem + 16384 + ((j * 4 + w) << 10));
    }
    __syncthreads();
#pragma unroll
    for (int kk = 0; kk < 2; kk++) {
      const int cp = ((kk << 6) + (g << 4)) ^ swz;
      u16x8 af[4], bfv[4];
#pragma unroll
      for (int mt = 0; mt < 4; mt++)
        af[mt] = *(const u16x8*)(smem + ((rowA + mt * 16) << 7) + cp);
#pragma unroll
      for (int nt = 0; nt < 4; nt++)
        bfv[nt] = *(const u16x8*)(smem + 16384 + ((rowB + nt * 16) << 7) + cp);
#pragma unroll
      for (int mt = 0; mt < 4; mt++)
#pragma unroll
        for (int nt = 0; nt < 4; nt++)
          acc[mt][nt] = MFMA(af[mt], bfv[nt], acc[mt][nt]);
    }
    __syncthreads();
  }

#pragma unroll
  for (int mt = 0; mt < 4; mt++) {
#pragma unroll
    for (int nt = 0; nt < 4; nt++) {
#pragma unroll
      for (int r = 0; r < 4; r++) {
        int m = bm0 + wr * 64 + mt * 16 + g * 4 + r;
        int n = bn0 + wc * 64 + nt * 16 + l15;
        float val = acc[mt][nt][r];
        if (EPI == 0) {
          int which = n >> 10;
          int hh = (n >> 6) & 15;
          int d = n & 63;
          int bb = m >> 11, s = m & 2047;
          int plane = bb * 16 + hh;
          unsigned short* o = (unsigned short*)outp;
          if (which == 0) {        // Q, pre-scaled by log2e
            o[(size_t)plane * 131072 + (size_t)s * 64 + d] = f2bf(val * L2E);
          } else if (which == 1) { // K
            o[4194304 + (size_t)plane * 131072 + (size_t)s * 64 + d] = f2bf(val);
          } else {                 // V^T: [plane][d][s]
            o[8388608 + (size_t)plane * 131072 + (size_t)d * 2048 + s] = f2bf(val);
          }
        } else {
          ((float*)outp)[(size_t)m * N + n] = val;
        }
      }
    }
  }
}

// ---------------------------------------------------------------------------
// Flash attention — r3 structure EXACTLY (grid 1024, 4 waves, 16 q/wave,
// 2-buffer LDS, defer-max), only the log2-domain changes applied.
__global__ __launch_bounds__(256) void k_attn(const unsigned short* __restrict__ qkv,
                                              const float* __restrict__ btab,
                                              unsigned short* __restrict__ ctx) {
  __shared__ __attribute__((aligned(16))) char smem[32768]; // 2 bufs x (K 8K + V 8K)
  const int tid = threadIdx.x;
  const int lane = tid & 63, w = tid >> 6;
  const int l15 = lane & 15, g = lane >> 4;

  // XCD-chunked swizzle: consecutive wg on one XCD share a plane
  const int wg = ((blockIdx.x & 7) << 7) + (blockIdx.x >> 3);
  const int plane = wg >> 5, qb = wg & 31;
  const int h = plane & 15, b = plane >> 4;
  const int q0 = (qb << 6) + (w << 4);

  const unsigned short* Qp = qkv + (size_t)plane * 131072;
  const unsigned short* Kp = qkv + 4194304 + (size_t)plane * 131072;
  const unsigned short* Vt = qkv + 8388608 + (size_t)plane * 131072;

  u16x8 qa[2];
#pragma unroll
  for (int kk = 0; kk < 2; kk++)
    qa[kk] = *(const u16x8*)(Qp + (size_t)(q0 + l15) * 64 + kk * 32 + g * 8);

  float m_r = -1e30f;
  f32x4 oacc[4], lacc;
#pragma unroll
  for (int t = 0; t < 4; t++) oacc[t] = (f32x4)0.0f;
  lacc = (f32x4)0.0f;

  const float* brow = btab + h * 4095 + 2047 - q0;
  const float cpos = btab[h * 4095 + 2047 + 1024];
  const float cneg = btab[h * 4095 + 2047 - 1024];

  u16x8 ones;
  {
    u32x4 ov = {0x3F803F80u, 0x3F803F80u, 0x3F803F80u, 0x3F803F80u};
    ones = __builtin_bit_cast(u16x8, ov);
  }

  // staging source addrs (pre-swizzled, linear LDS dest)
  const int srow = (w << 3) + (lane >> 3);   // 0..31
  const int soff = ((lane & 7) ^ (srow & 7)) << 4;
  const char* Ksrc = (const char*)Kp + (size_t)srow * 128 + soff;
  const char* Vsrc = (const char*)Vt + (size_t)srow * 4096 + soff;

  auto STAGE = [&](int t, int bsel) {
    char* sb = smem + (bsel << 14) + (w << 10);
    const char* ka = Ksrc + (size_t)t * 8192;
    gload16(ka, sb);
    gload16(ka + 4096, sb + 4096);
    const char* va = Vsrc + (size_t)t * 128;
    gload16(va, sb + 8192);
    gload16(va + 131072, sb + 12288);
  };

  STAGE(0, 0);
  __syncthreads();

  for (int t = 0; t < 32; ++t) {
    const int c = t & 1;
    if (t < 31) STAGE(t + 1, c ^ 1);
    const char* kb = smem + (c << 14);
    const char* vbuf = kb + 8192;
    const int kv = t << 6;

    // S^T = K Q^T : lane holds S^T[key = nt*16 + g*4 + r][q = q0 + l15]
    f32x4 s[4];
    __builtin_amdgcn_s_setprio(1);
#pragma unroll
    for (int nt = 0; nt < 4; nt++) {
      int keyr = nt * 16 + l15;
      int sw = (keyr & 7) << 4;
      u16x8 kb0 = *(const u16x8*)(kb + (keyr << 7) + ((g << 4) ^ sw));
      u16x8 kb1 = *(const u16x8*)(kb + (keyr << 7) + ((64 + (g << 4)) ^ sw));
      f32x4 z = (f32x4)0.0f;
      z = MFMA(kb0, qa[0], z);
      z = MFMA(kb1, qa[1], z);
      s[nt] = z;
    }
    __builtin_amdgcn_s_setprio(0);

    // bias (log2 domain): far tiles have saturated (constant) bucket
    int delta = kv - q0;
    float cb;
    if (delta >= 112 || delta <= -160) {
      cb = delta > 0 ? cpos : cneg;
    } else {
      cb = 0.0f;
      const float* bp = brow + kv + (g << 2) - l15;
#pragma unroll
      for (int nt = 0; nt < 4; nt++)
#pragma unroll
        for (int r = 0; r < 4; r++) s[nt][r] += bp[nt * 16 + r];
    }

    // local max over this lane's 16 scores (partial row max)
    float m1 = fmaxf(fmaxf(s[0][0], s[0][1]), s[0][2]);
    float m2 = fmaxf(fmaxf(s[0][3], s[1][0]), s[1][1]);
    float m3 = fmaxf(fmaxf(s[1][2], s[1][3]), s[2][0]);
    float m4 = fmaxf(fmaxf(s[2][1], s[2][2]), s[2][3]);
    float m5 = fmaxf(fmaxf(s[3][0], s[3][1]), s[3][2]);
    float mloc = fmaxf(fmaxf(fmaxf(m1, m2), fmaxf(m3, m4)), fmaxf(m5, s[3][3]));

    if (!__all(mloc + cb <= m_r + 12.0f)) {   // defer-max (log2 domain)
      float mxrow = fmaxf(mloc, __shfl_xor(mloc, 16));
      mxrow = fmaxf(mxrow, __shfl_xor(mxrow, 32));
      float mnew = fmaxf(m_r, mxrow + cb);
      float alpha = exp2f(m_r - mnew);
      m_r = mnew;
      float a4[4];
#pragma unroll
      for (int r = 0; r < 4; r++) a4[r] = __shfl(alpha, (g << 2) + r);
#pragma unroll
      for (int tt = 0; tt < 4; tt++) {
        f32x4 o = oacc[tt];
        o[0] *= a4[0]; o[1] *= a4[1]; o[2] *= a4[2]; o[3] *= a4[3];
        oacc[tt] = o;
      }
      lacc[0] *= a4[0]; lacc[1] *= a4[1]; lacc[2] *= a4[2]; lacc[3] *= a4[3];
    }

    // P = 2^(s + cb - m), bias (or const) folded into eb
    float eb = cb - m_r;
#pragma unroll
    for (int nt = 0; nt < 4; nt++)
#pragma unroll
      for (int r = 0; r < 4; r++)
        s[nt][r] = __builtin_amdgcn_exp2f(s[nt][r] + eb);

    // pack P -> bf16 pairs, then permlane-swap into PV A-fragments
    unsigned int wpk[4][2];
#pragma unroll
    for (int nt = 0; nt < 4; nt++) {
      wpk[nt][0] = cvtpk(s[nt][0], s[nt][1]);
      wpk[nt][1] = cvtpk(s[nt][2], s[nt][3]);
    }
    u16x8 pa[2];
#pragma unroll
    for (int kk = 0; kk < 2; kk++) {
      unsigned int X0 = wpk[2 * kk][0], Y0 = wpk[2 * kk + 1][0];
      asm volatile("v_permlane32_swap_b32 %0, %1" : "+v"(X0), "+v"(Y0));
      asm volatile("v_permlane16_swap_b32 %0, %1" : "+v"(X0), "+v"(Y0));
      unsigned int X1 = wpk[2 * kk][1], Y1 = wpk[2 * kk + 1][1];
      asm volatile("v_permlane32_swap_b32 %0, %1" : "+v"(X1), "+v"(Y1));
      asm volatile("v_permlane16_swap_b32 %0, %1" : "+v"(X1), "+v"(Y1));
      u32x4 pw = {X0, X1, Y0, Y1};   // words w0,w1,w2,w3
      pa[kk] = __builtin_bit_cast(u16x8, pw);
    }

    // O += P V ; l += P * ones
    __builtin_amdgcn_s_setprio(1);
#pragma unroll
    for (int tt = 0; tt < 4; tt++) {
      int d = tt * 16 + l15;
      int sw = (d & 7) << 4;
      u16x8 vb0 = *(const u16x8*)(vbuf + (d << 7) + ((g << 4) ^ sw));
      u16x8 vb1 = *(const u16x8*)(vbuf + (d << 7) + ((64 + (g << 4)) ^ sw));
      oacc[tt] = MFMA(pa[0], vb0, oacc[tt]);
      oacc[tt] = MFMA(pa[1], vb1, oacc[tt]);
    }
    lacc = MFMA(pa[0], ones, lacc);
    lacc = MFMA(pa[1], ones, lacc);
    __builtin_amdgcn_s_setprio(0);

    __syncthreads();
  }

#pragma unroll
  for (int r = 0; r < 4; r++) {
    float inv = 1.0f / lacc[r];
    size_t rowoff = ((size_t)(b * 2048 + q0 + (g << 2) + r) << 10) + h * 64;
#pragma unroll
    for (int tt = 0; tt < 4; tt++)
      ctx[rowoff + tt * 16 + l15] = f2bf(oacc[tt][r] * inv);
  }
}

// ---------------------------------------------------------------------------
extern "C" void kernel_launch(void* const* d_in, const int* in_sizes, int n_in,
                              void* d_out, int out_size, void* d_ws, size_t ws_size,
                              hipStream_t stream) {
  const float* hs = (const float*)d_in[0];
  const float* wq = (const float*)d_in[1];
  const float* wk = (const float*)d_in[2];
  const float* wv = (const float*)d_in[3];
  const float* wo = (const float*)d_in[4];
  const float* re = (const float*)d_in[5];

  if (ws_size < 50593728u) return;

  char* ws = (char*)d_ws;
  unsigned short* hsb = (unsigned short*)(ws);              // [4096][1024] bf16
  unsigned short* wt  = (unsigned short*)(ws + 8388608);    // [3072][1024] bf16
  unsigned short* wot = (unsigned short*)(ws + 14680064);   // [1024][1024] bf16
  unsigned short* qkv = (unsigned short*)(ws + 16777216);   // q,k [p][s][d]; v^T [p][d][s]
  unsigned short* ctx = (unsigned short*)(ws + 41943040);   // [4096][1024] bf16
  float*          btab = (float*)(ws + 50331648);           // [16][4095] fp32 (x log2e)

  k_cvt<<<4096, 256, 0, stream>>>(hs, hsb, 1048576);
  k_tc<<<dim3(16, 16), 256, 0, stream>>>(wq, wt, 1024, 1024);
  k_tc<<<dim3(16, 16), 256, 0, stream>>>(wk, wt + 1048576, 1024, 1024);
  k_tc<<<dim3(16, 16), 256, 0, stream>>>(wv, wt + 2097152, 1024, 1024);
  k_tc<<<dim3(16, 16), 256, 0, stream>>>(wo, wot, 1024, 1024);
  k_bias<<<256, 256, 0, stream>>>(re, btab);

  k_gemm<0><<<dim3(24, 32), 256, 0, stream>>>(hsb, wt, qkv, 4096, 3072, 1024);
  k_attn<<<1024, 256, 0, stream>>>(qkv, btab, ctx);
  k_gemm<1><<<dim3(8, 32), 256, 0, stream>>>(ctx, wot, d_out, 4096, 1024, 1024);
}